// Round 6
// baseline (703.272 us; speedup 1.0000x reference)
//
#include <hip/hip_runtime.h>

// DecoderStack: B=4,T=1024,D=1024,H=16,DK=DV=64,FF=4096
// Faithful quirks: softmax over QUERY axis (column softmax over t) — done as
// E=exp(S) in scores epilogue + column sums l_s via atomics + V scaled by 1/l_s;
// sub_norm(o) = o - mean - std (ddof=1).
// bf16 MFMA 16x16x32, fp32 accumulate, global_load_lds staging, XOR-swizzled
// LDS, XCD swizzles, split-K, LDS-staged coalesced epilogue stores.

typedef unsigned short u16;
typedef __bf16 bf16x8 __attribute__((ext_vector_type(8)));
typedef float f32x4 __attribute__((ext_vector_type(4)));

__device__ __forceinline__ u16 f2bf(float f) {
    unsigned int u = __float_as_uint(f);
    u += 0x7fffu + ((u >> 16) & 1u);   // RNE; inputs are finite
    return (u16)(u >> 16);
}
__device__ __forceinline__ float bf2f(u16 b) {
    return __uint_as_float(((unsigned int)b) << 16);
}

typedef __attribute__((address_space(1))) const void* as1cv;
typedef __attribute__((address_space(3))) void* as3v;
__device__ __forceinline__ void gl_lds16(const void* g, void* l) {
    __builtin_amdgcn_global_load_lds((as1cv)g, (as3v)l, 16, 0, 0);
}

// ---------------- converts / packs ----------------

__global__ __launch_bounds__(256) void convert_f2b_k(const float* __restrict__ in, u16* __restrict__ out) {
    long i = (long)blockIdx.x * 256 + threadIdx.x;
    float4 v = reinterpret_cast<const float4*>(in)[i];
    ushort4 o;
    o.x = f2bf(v.x); o.y = f2bf(v.y); o.z = f2bf(v.z); o.w = f2bf(v.w);
    reinterpret_cast<ushort4*>(out)[i] = o;
}

// out[p][r][q] = in[p][q][r] (fp32->bf16), LDS-tiled. grid (R/64, Q/64, P)
__global__ __launch_bounds__(256) void pack_perm_t(const float* __restrict__ in, u16* __restrict__ out,
                                                   int Q, int R) {
    __shared__ float tile[64][65];
    int p = blockIdx.z;
    int r0 = blockIdx.x * 64, q0 = blockIdx.y * 64;
    int tx = threadIdx.x & 63, ty = threadIdx.x >> 6;
    const float* inp = in + ((long)p * Q + q0) * R + r0;
    #pragma unroll
    for (int i = 0; i < 64; i += 4)
        tile[ty + i][tx] = inp[(long)(ty + i) * R + tx];
    __syncthreads();
    u16* outp = out + ((long)p * R + r0) * Q + q0;
    #pragma unroll
    for (int i = 0; i < 64; i += 4)
        outp[(long)(ty + i) * Q + tx] = f2bf(tile[tx][ty + i]);
}

// 64x64 tiled bf16 transpose: out[c][r] = in[r][c], batched over z
__global__ __launch_bounds__(256) void transpose_k(const u16* __restrict__ in, long ld_in, long z_in,
                                                   u16* __restrict__ out, long ld_out, long z_out) {
    __shared__ u16 tile[64][66];
    const u16* inz = in + (long)blockIdx.z * z_in;
    u16* outz = out + (long)blockIdx.z * z_out;
    int r0 = blockIdx.y * 64;
    int c0 = blockIdx.x * 64;
    int tx = threadIdx.x & 63, ty = threadIdx.x >> 6;
    #pragma unroll
    for (int i = 0; i < 64; i += 4)
        tile[ty + i][tx] = inz[(long)(r0 + ty + i) * ld_in + c0 + tx];
    __syncthreads();
    #pragma unroll
    for (int i = 0; i < 64; i += 4)
        outz[(long)(c0 + ty + i) * ld_out + r0 + tx] = tile[tx][ty + i];
}

// ---------------- GEMM: C[M][N] = alpha * A[M][K] x Bt[N][K]^T ----------------
// SWZ=0: 3D grid (x,y,z). SWZ=4: 1D grid, XCD-slab my=(L&7)*4+((L>>3)&3),
// mx=L>>5; KS>1: split-K chunk = L>>9. SWZ=5: scores head-locality (z=head:
// each XCD owns 2 heads; grid 1024 = 8 xcd * 2 head * 8 bx * 8 by).
// EPI: 0 none, 1 +bias+relu, 2 +bias, 3 exp + atomic column-sum into csum.
// Epilogue: fragments staged to LDS (padded rows), then coalesced int4 stores.
template<int BM, int BN, int BK, int WM, int WN, int OUT_BF16, int EPI, int SWZ, int KS>
__global__ __launch_bounds__(256) void gemm_k(
    const u16* __restrict__ A, long lda, long a_zin, long a_zout,
    const u16* __restrict__ B, long ldb, long b_zin, long b_zout,
    void* __restrict__ Cv, long ldc, long c_zin, long c_zout,
    int zin, int K, float alpha, const float* __restrict__ bias,
    float* __restrict__ csum)
{
    static_assert(BK == 64, "staging assumes BK=64");
    constexpr int WTM = BM / WM;
    constexpr int WTN = BN / WN;
    constexpr int TM = WTM / 16;
    constexpr int TN = WTN / 16;
    __shared__ __align__(16) u16 smem[(BM + BN) * BK];
    u16* As = smem;
    u16* Bs = smem + BM * BK;

    int bx, by, z;
    if (SWZ == 4) {
        int L = blockIdx.x;
        if (KS > 1) { z = L >> 9; L &= 511; } else { z = 0; }
        by = (L & 7) * 4 + ((L >> 3) & 3);
        bx = L >> 5;
    } else if (SWZ == 5) {
        int L = blockIdx.x;
        z = (L & 7) * 2 + ((L >> 3) & 1);
        bx = (L >> 4) & 7;
        by = L >> 7;
    } else {
        bx = blockIdx.x; by = blockIdx.y; z = blockIdx.z;
    }
    int zi = z % zin, zo = z / zin;
    A += (long)zi * a_zin + (long)zo * a_zout;
    B += (long)zi * b_zin + (long)zo * b_zout;
    long coff = (long)zi * c_zin + (long)zo * c_zout;

    int tid = threadIdx.x;
    int lane = tid & 63;
    int wave = tid >> 6;
    int wm = wave / WN, wn = wave % WN;
    long bm0 = (long)by * BM, bn0 = (long)bx * BN;

    f32x4 acc[TM][TN];
    #pragma unroll
    for (int i = 0; i < TM; ++i)
        #pragma unroll
        for (int j = 0; j < TN; ++j) {
            acc[i][j][0] = 0.f; acc[i][j][1] = 0.f;
            acc[i][j][2] = 0.f; acc[i][j][3] = 0.f;
        }

    int r16 = lane & 15;
    int quad = lane >> 4;
    int l8 = lane >> 3;                    // stripe row
    int gsw = ((lane & 7) ^ l8) * 8;       // swizzled global col (elements)

    constexpr int ASTR = BM / 8;
    constexpr int BSTR = BN / 8;

    for (int k0 = 0; k0 < K; k0 += BK) {
        #pragma unroll
        for (int s = wave; s < ASTR; s += 4)
            gl_lds16(&A[(bm0 + s * 8 + l8) * lda + k0 + gsw], &As[s * 512]);
        #pragma unroll
        for (int s = wave; s < BSTR; s += 4)
            gl_lds16(&B[(bn0 + s * 8 + l8) * ldb + k0 + gsw], &Bs[s * 512]);
        __syncthreads();
        #pragma unroll
        for (int kk = 0; kk < BK; kk += 32) {
            int cb = (kk >> 3) + quad;
            bf16x8 av[TM], bv[TN];
            #pragma unroll
            for (int i = 0; i < TM; ++i) {
                int r = wm * WTM + i * 16 + r16;
                av[i] = *reinterpret_cast<const bf16x8*>(&As[r * 64 + ((cb ^ (r & 7)) * 8)]);
            }
            #pragma unroll
            for (int j = 0; j < TN; ++j) {
                int r = wn * WTN + j * 16 + r16;
                bv[j] = *reinterpret_cast<const bf16x8*>(&Bs[r * 64 + ((cb ^ (r & 7)) * 8)]);
            }
            #pragma unroll
            for (int i = 0; i < TM; ++i)
                #pragma unroll
                for (int j = 0; j < TN; ++j)
                    acc[i][j] = __builtin_amdgcn_mfma_f32_16x16x32_bf16(av[i], bv[j], acc[i][j], 0, 0, 0);
        }
        __syncthreads();
    }

    // ---- LDS-staged epilogue. C/D frag: col=lane&15, row=quad*4+reg ----
    constexpr int EB = OUT_BF16 ? 2 : 4;     // bytes per out elem
    constexpr int CH = 16 / EB;              // elems per 16B chunk
    constexpr int STRIDE = BN + CH;          // padded LDS row (elems)
    constexpr int LDSB = (BM + BN) * BK * 2;
    constexpr int EPASS = (BM * STRIDE * EB > LDSB) ? 2 : 1;
    constexpr int RPP = BM / EPASS;
    static_assert(RPP * STRIDE * EB <= LDSB, "epilogue tile overflows LDS");
    static_assert(EPASS == 1 || (WM == 2 && WTM == RPP), "pass/wave row alignment");
    constexpr int CPR = BN / CH;             // chunks per row
    constexpr int NCH = RPP * CPR / 256;     // chunks per thread per pass
    static_assert(RPP * CPR % 256 == 0, "store mapping");

    int rb = quad * 4;
    float csl[TN];
    #pragma unroll
    for (int j = 0; j < TN; ++j) csl[j] = 0.f;

    float* Ef = reinterpret_cast<float*>(smem);
    char* Cb = reinterpret_cast<char*>(Cv);

    for (int pass = 0; pass < EPASS; ++pass) {
        int p0 = pass * RPP;
        __syncthreads();
        #pragma unroll
        for (int i = 0; i < TM; ++i) {
            #pragma unroll
            for (int j = 0; j < TN; ++j) {
                int lcol = wn * WTN + j * 16 + r16;
                float bsv = (EPI == 1 || EPI == 2) ? bias[bn0 + lcol] : 0.f;
                #pragma unroll
                for (int r = 0; r < 4; ++r) {
                    int lrow = wm * WTM + i * 16 + rb + r;
                    if ((unsigned)(lrow - p0) < (unsigned)RPP) {
                        float v = acc[i][j][r] * alpha;
                        if (EPI == 1) { v += bsv; v = v > 0.f ? v : 0.f; }
                        else if (EPI == 2) { v += bsv; }
                        else if (EPI == 3) { v = __expf(v); csl[j] += v; }
                        if (OUT_BF16) smem[(lrow - p0) * STRIDE + lcol] = f2bf(v);
                        else          Ef[(lrow - p0) * STRIDE + lcol] = v;
                    }
                }
            }
        }
        __syncthreads();
        #pragma unroll
        for (int c = 0; c < NCH; ++c) {
            int cid = tid + c * 256;
            int row = cid / CPR, ch = cid - row * CPR;
            int4 v = *reinterpret_cast<const int4*>(
                reinterpret_cast<const char*>(smem) + (row * STRIDE + ch * CH) * EB);
            long gidx = coff + (bm0 + p0 + row) * ldc + bn0 + ch * CH;
            *reinterpret_cast<int4*>(Cb + gidx * EB) = v;
        }
    }

    if (EPI == 3) {
        #pragma unroll
        for (int j = 0; j < TN; ++j) {
            float cs = csl[j];
            cs += __shfl_xor(cs, 16, 64);
            cs += __shfl_xor(cs, 32, 64);
            if (quad == 0) {
                long col = bn0 + wn * WTN + j * 16 + r16;
                atomicAdd(&csum[(long)zi * 1024 + col], cs);
            }
        }
    }
}

// ---------------- Vt *= 1/l : Vt slab [1024 hv][1024 s], csum [16][1024] ----------------
__global__ __launch_bounds__(256) void vscale_k(u16* __restrict__ Vt, const float* __restrict__ csum) {
    long idx = (long)blockIdx.x * 256 + threadIdx.x;   // grid 512
    int hv = (int)(idx >> 7);
    int s8 = ((int)idx & 127) * 8;
    const float* cs = csum + (hv >> 6) * 1024 + s8;
    u16* pv = Vt + (long)hv * 1024 + s8;
    ushort4 a = *reinterpret_cast<ushort4*>(pv);
    ushort4 b = *reinterpret_cast<ushort4*>(pv + 4);
    a.x = f2bf(bf2f(a.x) / cs[0]); a.y = f2bf(bf2f(a.y) / cs[1]);
    a.z = f2bf(bf2f(a.z) / cs[2]); a.w = f2bf(bf2f(a.w) / cs[3]);
    b.x = f2bf(bf2f(b.x) / cs[4]); b.y = f2bf(bf2f(b.y) / cs[5]);
    b.z = f2bf(bf2f(b.z) / cs[6]); b.w = f2bf(bf2f(b.w) / cs[7]);
    *reinterpret_cast<ushort4*>(pv) = a;
    *reinterpret_cast<ushort4*>(pv + 4) = b;
}

// ---------------- out = (sum of NP partial slabs + resid [+bias]) - mean - std ----------------
template<int NP, int BIAS>
__global__ __launch_bounds__(256) void addsn_k(const float* __restrict__ parts, long pstride,
                                               const float* __restrict__ resid,
                                               const float* __restrict__ bias,
                                               float* __restrict__ out) {
    __shared__ float sm[8];
    long row = blockIdx.x;
    int tid = threadIdx.x;
    float4 x = reinterpret_cast<const float4*>(resid + row * 1024)[tid];
    #pragma unroll
    for (int p = 0; p < NP; ++p) {
        float4 a = reinterpret_cast<const float4*>(parts + p * pstride + row * 1024)[tid];
        x.x += a.x; x.y += a.y; x.z += a.z; x.w += a.w;
    }
    if (BIAS) {
        float4 bb = reinterpret_cast<const float4*>(bias)[tid];
        x.x += bb.x; x.y += bb.y; x.z += bb.z; x.w += bb.w;
    }
    float s = x.x + x.y + x.z + x.w;
    for (int o = 32; o > 0; o >>= 1) s += __shfl_down(s, o, 64);
    int lane = tid & 63, w = tid >> 6;
    if (lane == 0) sm[w] = s;
    __syncthreads();
    float mean = (sm[0] + sm[1] + sm[2] + sm[3]) * (1.f / 1024.f);
    float d0 = x.x - mean, d1 = x.y - mean, d2 = x.z - mean, d3 = x.w - mean;
    float q = d0 * d0 + d1 * d1 + d2 * d2 + d3 * d3;
    for (int o = 32; o > 0; o >>= 1) q += __shfl_down(q, o, 64);
    if (lane == 0) sm[w + 4] = q;
    __syncthreads();
    float sd = sqrtf((sm[4] + sm[5] + sm[6] + sm[7]) * (1.f / 1023.f));
    float4 ov;
    ov.x = d0 - sd; ov.y = d1 - sd; ov.z = d2 - sd; ov.w = d3 - sd;
    reinterpret_cast<float4*>(out + row * 1024)[tid] = ov;
}

// ---------------- launcher ----------------

extern "C" void kernel_launch(void* const* d_in, const int* in_sizes, int n_in,
                              void* d_out, int out_size, void* d_ws, size_t ws_size,
                              hipStream_t stream) {
    (void)in_sizes; (void)n_in; (void)out_size; (void)ws_size;
    const float* xf   = (const float*)d_in[0];
    const float* yf   = (const float*)d_in[1];
    const float* Wq1  = (const float*)d_in[2];
    const float* Wk1  = (const float*)d_in[3];
    const float* Wv1  = (const float*)d_in[4];
    const float* Wo1  = (const float*)d_in[5];
    const float* Wq2  = (const float*)d_in[6];
    const float* Wk2  = (const float*)d_in[7];
    const float* Wv2  = (const float*)d_in[8];
    const float* Wo2  = (const float*)d_in[9];
    const float* W_in = (const float*)d_in[10];
    const float* b_in = (const float*)d_in[11];
    const float* W_out= (const float*)d_in[12];
    const float* b_out= (const float*)d_in[13];

    // workspace layout (~192 MB)
    char* p = (char*)d_ws;
    auto alloc = [&](size_t bytes) { char* r = p; p += bytes; return r; };
    u16*   yb    = (u16*)alloc(8388608);    // y bf16 (4096x1024)
    u16*   xb    = (u16*)alloc(8388608);    // x bf16
    u16*   W1cat = (u16*)alloc(8388608);    // [Wq1|Wk1|Wv1|Wq2]^T-packed (4096 x 1024)
    u16*   Wkv2t = (u16*)alloc(4194304);    // [Wk2|Wv2] (2048 x 1024)
    u16*   Wo1t  = (u16*)alloc(2097152);
    u16*   Wo2t  = (u16*)alloc(2097152);
    u16*   Winb  = (u16*)alloc(8388608);    // W_in (4096 x 1024) = Bt layout
    u16*   Woutb = (u16*)alloc(8388608);    // W_out (1024 x 4096) = Bt layout
    u16*   QKV   = (u16*)alloc(33554432);   // (4096 x 4096): [Q1|K1|V1|Q2] per (b,t)
    u16*   KV2   = (u16*)alloc(16777216);   // (4096 x 2048): [K2|V2]
    u16*   Vt    = (u16*)alloc(8388608);    // per b: (1024 hv x 1024 s), scaled by 1/l in place
    u16*   Pb    = (u16*)alloc(33554432);   // per b: E=exp(S) [16][1024 t][1024 s]; reused as FFN hidden
    float* csum  = (float*)alloc(65536);    // column sums l_s [16][1024]
    u16*   part  = (u16*)alloc(8388608);    // attn partial (4096 x 1024) bf16
    float* gout  = (float*)alloc(33554432); // fp32 split-K partials, 2 slabs of 16 MB
    float* out1  = (float*)alloc(16777216);

    // ---- converts + weight packs ----
    convert_f2b_k<<<4096, 256, 0, stream>>>(yf, yb);
    convert_f2b_k<<<4096, 256, 0, stream>>>(xf, xb);
    pack_perm_t<<<dim3(1, 16, 16), 256, 0, stream>>>(Wq1, W1cat,           1024, 64);
    pack_perm_t<<<dim3(1, 16, 16), 256, 0, stream>>>(Wk1, W1cat + 1048576, 1024, 64);
    pack_perm_t<<<dim3(1, 16, 16), 256, 0, stream>>>(Wv1, W1cat + 2097152, 1024, 64);
    pack_perm_t<<<dim3(1, 16, 16), 256, 0, stream>>>(Wq2, W1cat + 3145728, 1024, 64);
    pack_perm_t<<<dim3(1, 16, 16), 256, 0, stream>>>(Wk2, Wkv2t,           1024, 64);
    pack_perm_t<<<dim3(1, 16, 16), 256, 0, stream>>>(Wv2, Wkv2t + 1048576, 1024, 64);
    pack_perm_t<<<dim3(16, 16, 1), 256, 0, stream>>>(Wo1, Wo1t,            1024, 1024);
    pack_perm_t<<<dim3(16, 16, 1), 256, 0, stream>>>(Wo2, Wo2t,            1024, 1024);
    convert_f2b_k<<<4096, 256, 0, stream>>>(W_in,  Winb);
    convert_f2b_k<<<4096, 256, 0, stream>>>(W_out, Woutb);

    // attention core: E=exp(QK^T/8) + atomic l_s; Vt scaled by 1/l_s; PV.
    auto run_attention = [&](const u16* Q, long ldq, long qz,
                             const u16* Kp, long ldk, long kz,
                             const u16* Vp, long ldv, long vz) {
        transpose_k<<<dim3(16, 16, 4), 256, 0, stream>>>(Vp, ldv, vz, Vt, 1024L, 1048576L);
        for (int b = 0; b < 4; ++b) {
            hipMemsetAsync(csum, 0, 65536, stream);
            gemm_k<128,128,64,2,2,1,3,5,1><<<1024, 256, 0, stream>>>(
                Q + b * qz, ldq, 64L, 0L, Kp + b * kz, ldk, 64L, 0L,
                (void*)Pb, 1024L, 1048576L, 0L, 16, 64, 0.125f, nullptr, csum);
            vscale_k<<<512, 256, 0, stream>>>(Vt + (long)b * 1048576, csum);
            gemm_k<64,64,64,2,2,1,0,0,1><<<dim3(1, 16, 16), 256, 0, stream>>>(
                Pb, 1024L, 1048576L, 0L, Vt + (long)b * 1048576, 1024L, 65536L, 0L,
                (void*)(part + (long)b * 1048576), 1024L, 64L, 0L, 16, 1024, 1.0f, nullptr, nullptr);
        }
    };

    // ---- fused projections: QKV1 + Q2 (both consume y), N=4096 ----
    gemm_k<128,128,64,2,2,1,0,4,1><<<dim3(32 * 32), 256, 0, stream>>>(
        yb, 1024L, 0L, 0L, W1cat, 1024L, 0L, 0L, (void*)QKV, 4096L, 0L, 0L, 1, 1024, 1.0f, nullptr, nullptr);
    // K2/V2 from x, N=2048
    gemm_k<128,128,64,2,2,1,0,4,1><<<dim3(16 * 32), 256, 0, stream>>>(
        xb, 1024L, 0L, 0L, Wkv2t, 1024L, 0L, 0L, (void*)KV2, 2048L, 0L, 0L, 1, 1024, 1.0f, nullptr, nullptr);

    // ---- MHA1 (self-attn on y): Q/K/V at cols 0/1024/2048 of QKV ----
    run_attention(QKV, 4096L, 4194304L, QKV + 1024, 4096L, 4194304L, QKV + 2048, 4096L, 4194304L);
    gemm_k<128,64,64,2,2,0,0,4,2><<<dim3(2 * 512), 256, 0, stream>>>(
        part, 1024L, 0L, 512L, Wo1t, 1024L, 0L, 512L,
        (void*)gout, 1024L, 0L, 4194304L, 1, 512, 1.0f, nullptr, nullptr);
    addsn_k<2,0><<<4096, 256, 0, stream>>>(gout, 4194304L, yf, nullptr, out1);

    // ---- MHA2 (q from y at QKV col 3072; k/v from x in KV2) ----
    run_attention(QKV + 3072, 4096L, 4194304L, KV2, 2048L, 2097152L, KV2 + 1024, 2048L, 2097152L);
    gemm_k<128,64,64,2,2,0,0,4,2><<<dim3(2 * 512), 256, 0, stream>>>(
        part, 1024L, 0L, 512L, Wo2t, 1024L, 0L, 512L,
        (void*)gout, 1024L, 0L, 4194304L, 1, 512, 1.0f, nullptr, nullptr);
    addsn_k<2,0><<<4096, 256, 0, stream>>>(gout, 4194304L, out1, nullptr, (float*)d_out);

    // ---- FFN on y (hidden reuses Pb: 4096x4096 bf16) ----
    gemm_k<128,128,64,2,2,1,1,4,1><<<dim3(32 * 32), 256, 0, stream>>>(
        yb, 1024L, 0L, 0L, Winb, 1024L, 0L, 0L, (void*)Pb, 4096L, 0L, 0L, 1, 1024, 1.0f, b_in, nullptr);
    gemm_k<128,64,64,2,2,0,0,4,2><<<dim3(2 * 512), 256, 0, stream>>>(
        Pb, 4096L, 0L, 2048L, Woutb, 4096L, 0L, 2048L,
        (void*)gout, 1024L, 0L, 4194304L, 1, 2048, 1.0f, nullptr, nullptr);
    addsn_k<2,1><<<4096, 256, 0, stream>>>(gout, 4194304L, (const float*)d_out, b_out, (float*)d_out);
}

// Round 7
// 527.121 us; speedup vs baseline: 1.3342x; 1.3342x over previous
//
#include <hip/hip_runtime.h>

// DecoderStack: B=4,T=1024,D=1024,H=16,DK=DV=64,FF=4096
// Softmax over QUERY axis: l_s = sum_t exp(S) via store-free l-pass (EPI=4),
// 1/l_s folded into V (vscale), then fused attn_pv_k recomputes E per tile in
// LDS and multiplies by V — E never touches HBM.
// sub_norm(o) = o - mean - std (ddof=1).

typedef unsigned short u16;
typedef __bf16 bf16x8 __attribute__((ext_vector_type(8)));
typedef float f32x4 __attribute__((ext_vector_type(4)));

__device__ __forceinline__ u16 f2bf(float f) {
    unsigned int u = __float_as_uint(f);
    u += 0x7fffu + ((u >> 16) & 1u);   // RNE; inputs are finite
    return (u16)(u >> 16);
}
__device__ __forceinline__ float bf2f(u16 b) {
    return __uint_as_float(((unsigned int)b) << 16);
}

typedef __attribute__((address_space(1))) const void* as1cv;
typedef __attribute__((address_space(3))) void* as3v;
__device__ __forceinline__ void gl_lds16(const void* g, void* l) {
    __builtin_amdgcn_global_load_lds((as1cv)g, (as3v)l, 16, 0, 0);
}

// ---------------- converts / packs ----------------

__global__ __launch_bounds__(256) void convert_f2b_k(const float* __restrict__ in, u16* __restrict__ out) {
    long i = (long)blockIdx.x * 256 + threadIdx.x;
    float4 v = reinterpret_cast<const float4*>(in)[i];
    ushort4 o;
    o.x = f2bf(v.x); o.y = f2bf(v.y); o.z = f2bf(v.z); o.w = f2bf(v.w);
    reinterpret_cast<ushort4*>(out)[i] = o;
}

// out[p][r][q] = in[p][q][r] (fp32->bf16), LDS-tiled. grid (R/64, Q/64, P)
__global__ __launch_bounds__(256) void pack_perm_t(const float* __restrict__ in, u16* __restrict__ out,
                                                   int Q, int R) {
    __shared__ float tile[64][65];
    int p = blockIdx.z;
    int r0 = blockIdx.x * 64, q0 = blockIdx.y * 64;
    int tx = threadIdx.x & 63, ty = threadIdx.x >> 6;
    const float* inp = in + ((long)p * Q + q0) * R + r0;
    #pragma unroll
    for (int i = 0; i < 64; i += 4)
        tile[ty + i][tx] = inp[(long)(ty + i) * R + tx];
    __syncthreads();
    u16* outp = out + ((long)p * R + r0) * Q + q0;
    #pragma unroll
    for (int i = 0; i < 64; i += 4)
        outp[(long)(ty + i) * Q + tx] = f2bf(tile[tx][ty + i]);
}

// 64x64 tiled bf16 transpose: out[c][r] = in[r][c], batched over z
__global__ __launch_bounds__(256) void transpose_k(const u16* __restrict__ in, long ld_in, long z_in,
                                                   u16* __restrict__ out, long ld_out, long z_out) {
    __shared__ u16 tile[64][66];
    const u16* inz = in + (long)blockIdx.z * z_in;
    u16* outz = out + (long)blockIdx.z * z_out;
    int r0 = blockIdx.y * 64;
    int c0 = blockIdx.x * 64;
    int tx = threadIdx.x & 63, ty = threadIdx.x >> 6;
    #pragma unroll
    for (int i = 0; i < 64; i += 4)
        tile[ty + i][tx] = inz[(long)(r0 + ty + i) * ld_in + c0 + tx];
    __syncthreads();
    #pragma unroll
    for (int i = 0; i < 64; i += 4)
        outz[(long)(c0 + ty + i) * ld_out + r0 + tx] = tile[tx][ty + i];
}

// ---------------- GEMM: C[M][N] = alpha * A[M][K] x Bt[N][K]^T ----------------
// SWZ=0: 3D grid (x,y,z). SWZ=4: 1D grid, XCD-slab my=(L&7)*4+((L>>3)&3),
// mx=L>>5; KS>1: split-K chunk = L>>9.
// EPI: 0 none, 1 +bias+relu, 2 +bias, 4 exp + atomic column-sum, NO C store.
// Store epilogue (EPI<4): fragments staged to LDS, coalesced int4 stores.
template<int BM, int BN, int BK, int WM, int WN, int OUT_BF16, int EPI, int SWZ, int KS>
__global__ __launch_bounds__(256) void gemm_k(
    const u16* __restrict__ A, long lda, long a_zin, long a_zout,
    const u16* __restrict__ B, long ldb, long b_zin, long b_zout,
    void* __restrict__ Cv, long ldc, long c_zin, long c_zout,
    int zin, int K, float alpha, const float* __restrict__ bias,
    float* __restrict__ csum)
{
    static_assert(BK == 64, "staging assumes BK=64");
    constexpr int WTM = BM / WM;
    constexpr int WTN = BN / WN;
    constexpr int TM = WTM / 16;
    constexpr int TN = WTN / 16;
    __shared__ __align__(16) u16 smem[(BM + BN) * BK];
    u16* As = smem;
    u16* Bs = smem + BM * BK;

    int bx, by, z;
    if (SWZ == 4) {
        int L = blockIdx.x;
        if (KS > 1) { z = L >> 9; L &= 511; } else { z = 0; }
        by = (L & 7) * 4 + ((L >> 3) & 3);
        bx = L >> 5;
    } else {
        bx = blockIdx.x; by = blockIdx.y; z = blockIdx.z;
    }
    int zi = z % zin, zo = z / zin;
    A += (long)zi * a_zin + (long)zo * a_zout;
    B += (long)zi * b_zin + (long)zo * b_zout;
    long coff = (long)zi * c_zin + (long)zo * c_zout;

    int tid = threadIdx.x;
    int lane = tid & 63;
    int wave = tid >> 6;
    int wm = wave / WN, wn = wave % WN;
    long bm0 = (long)by * BM, bn0 = (long)bx * BN;

    f32x4 acc[TM][TN];
    #pragma unroll
    for (int i = 0; i < TM; ++i)
        #pragma unroll
        for (int j = 0; j < TN; ++j) {
            acc[i][j][0] = 0.f; acc[i][j][1] = 0.f;
            acc[i][j][2] = 0.f; acc[i][j][3] = 0.f;
        }

    int r16 = lane & 15;
    int quad = lane >> 4;
    int l8 = lane >> 3;                    // stripe row
    int gsw = ((lane & 7) ^ l8) * 8;       // swizzled global col (elements)

    constexpr int ASTR = BM / 8;
    constexpr int BSTR = BN / 8;

    for (int k0 = 0; k0 < K; k0 += BK) {
        #pragma unroll
        for (int s = wave; s < ASTR; s += 4)
            gl_lds16(&A[(bm0 + s * 8 + l8) * lda + k0 + gsw], &As[s * 512]);
        #pragma unroll
        for (int s = wave; s < BSTR; s += 4)
            gl_lds16(&B[(bn0 + s * 8 + l8) * ldb + k0 + gsw], &Bs[s * 512]);
        __syncthreads();
        #pragma unroll
        for (int kk = 0; kk < BK; kk += 32) {
            int cb = (kk >> 3) + quad;
            bf16x8 av[TM], bv[TN];
            #pragma unroll
            for (int i = 0; i < TM; ++i) {
                int r = wm * WTM + i * 16 + r16;
                av[i] = *reinterpret_cast<const bf16x8*>(&As[r * 64 + ((cb ^ (r & 7)) * 8)]);
            }
            #pragma unroll
            for (int j = 0; j < TN; ++j) {
                int r = wn * WTN + j * 16 + r16;
                bv[j] = *reinterpret_cast<const bf16x8*>(&Bs[r * 64 + ((cb ^ (r & 7)) * 8)]);
            }
            #pragma unroll
            for (int i = 0; i < TM; ++i)
                #pragma unroll
                for (int j = 0; j < TN; ++j)
                    acc[i][j] = __builtin_amdgcn_mfma_f32_16x16x32_bf16(av[i], bv[j], acc[i][j], 0, 0, 0);
        }
        __syncthreads();
    }

    int rb = quad * 4;

    if (EPI == 4) {
        // exp + column sums only; no C store. csum layout [z][1024].
        float csl[TN];
        #pragma unroll
        for (int j = 0; j < TN; ++j) csl[j] = 0.f;
        #pragma unroll
        for (int i = 0; i < TM; ++i)
            #pragma unroll
            for (int j = 0; j < TN; ++j)
                #pragma unroll
                for (int r = 0; r < 4; ++r)
                    csl[j] += __expf(acc[i][j][r] * alpha);
        #pragma unroll
        for (int j = 0; j < TN; ++j) {
            float cs = csl[j];
            cs += __shfl_xor(cs, 16, 64);
            cs += __shfl_xor(cs, 32, 64);
            if (quad == 0) {
                long col = bn0 + wn * WTN + j * 16 + r16;
                atomicAdd(&csum[((long)zo * zin + zi) * 1024 + col], cs);
            }
        }
        return;
    }

    // ---- LDS-staged store epilogue ----
    constexpr int EB = OUT_BF16 ? 2 : 4;
    constexpr int CH = 16 / EB;
    constexpr int STRIDE = BN + CH;
    constexpr int LDSB = (BM + BN) * BK * 2;
    constexpr int EPASS = (BM * STRIDE * EB > LDSB) ? 2 : 1;
    constexpr int RPP = BM / EPASS;
    static_assert(RPP * STRIDE * EB <= LDSB, "epilogue tile overflows LDS");
    static_assert(EPASS == 1 || (WM == 2 && WTM == RPP), "pass/wave row alignment");
    constexpr int CPR = BN / CH;
    constexpr int NCH = RPP * CPR / 256;
    static_assert(RPP * CPR % 256 == 0, "store mapping");

    float* Ef = reinterpret_cast<float*>(smem);
    char* Cb = reinterpret_cast<char*>(Cv);

    for (int pass = 0; pass < EPASS; ++pass) {
        int p0 = pass * RPP;
        __syncthreads();
        #pragma unroll
        for (int i = 0; i < TM; ++i) {
            #pragma unroll
            for (int j = 0; j < TN; ++j) {
                int lcol = wn * WTN + j * 16 + r16;
                float bsv = (EPI == 1 || EPI == 2) ? bias[bn0 + lcol] : 0.f;
                #pragma unroll
                for (int r = 0; r < 4; ++r) {
                    int lrow = wm * WTM + i * 16 + rb + r;
                    if ((unsigned)(lrow - p0) < (unsigned)RPP) {
                        float v = acc[i][j][r] * alpha;
                        if (EPI == 1) { v += bsv; v = v > 0.f ? v : 0.f; }
                        else if (EPI == 2) { v += bsv; }
                        if (OUT_BF16) smem[(lrow - p0) * STRIDE + lcol] = f2bf(v);
                        else          Ef[(lrow - p0) * STRIDE + lcol] = v;
                    }
                }
            }
        }
        __syncthreads();
        #pragma unroll
        for (int c = 0; c < NCH; ++c) {
            int cid = tid + c * 256;
            int row = cid / CPR, ch = cid - row * CPR;
            int4 v = *reinterpret_cast<const int4*>(
                reinterpret_cast<const char*>(smem) + (row * STRIDE + ch * CH) * EB);
            long gidx = coff + (bm0 + p0 + row) * ldc + bn0 + ch * CH;
            *reinterpret_cast<int4*>(Cb + gidx * EB) = v;
        }
    }
}

// ---------------- fused attention PV: recompute E per tile, x scaled V ----------------
// Grid 512 blocks: L -> xcd=L&7: head=(L&7)*2+((L>>3)&1), tb=(L>>4)&7, b=L>>7.
// Per block: out[128 t][64 v] = sum_s exp(0.125*Q K^T) * Vt_scaled.
__global__ __launch_bounds__(256) void attn_pv_k(
    const u16* __restrict__ Qg, long ldq, long qbz,
    const u16* __restrict__ Kg, long ldk, long kbz,
    const u16* __restrict__ Vg,            // [b][1024 hv][1024 s], pre-scaled by 1/l
    u16* __restrict__ outg)                // part: [b][1024 t][1024 (h*64+v)]
{
    __shared__ __align__(16) u16 Qs[128 * 64];
    __shared__ __align__(16) u16 Ks[64 * 64];
    __shared__ __align__(16) u16 Vs[64 * 64];
    __shared__ __align__(16) u16 Es[128 * 64];

    int L = blockIdx.x;
    int h  = (L & 7) * 2 + ((L >> 3) & 1);
    int tb = (L >> 4) & 7;
    int b  = L >> 7;

    const u16* Q  = Qg + (long)b * qbz + h * 64;
    const u16* Kp = Kg + (long)b * kbz + h * 64;
    const u16* Vp = Vg + (long)b * 1048576 + (long)h * 65536;
    u16* outp = outg + (long)b * 1048576 + (long)tb * 131072 + h * 64;

    int tid = threadIdx.x, lane = tid & 63, wave = tid >> 6;
    int wm = wave >> 1, wn = wave & 1;
    int r16 = lane & 15, quad = lane >> 4, l8 = lane >> 3;
    int gsw = ((lane & 7) ^ l8) * 8;
    long t0 = (long)tb * 128;

    #pragma unroll
    for (int s = wave; s < 16; s += 4)
        gl_lds16(&Q[(t0 + s * 8 + l8) * ldq + gsw], &Qs[s * 512]);

    f32x4 acc[4][2];
    #pragma unroll
    for (int i = 0; i < 4; ++i)
        #pragma unroll
        for (int j = 0; j < 2; ++j) {
            acc[i][j][0] = 0.f; acc[i][j][1] = 0.f;
            acc[i][j][2] = 0.f; acc[i][j][3] = 0.f;
        }

    for (int sc = 0; sc < 16; ++sc) {
        #pragma unroll
        for (int s = wave; s < 8; s += 4) {
            gl_lds16(&Kp[(long)(sc * 64 + s * 8 + l8) * ldk + gsw], &Ks[s * 512]);
            gl_lds16(&Vp[(long)(s * 8 + l8) * 1024 + sc * 64 + gsw], &Vs[s * 512]);
        }
        __syncthreads();                       // K/V (and Q on sc==0) staged

        // E-chunk = Q x K^T (128x64, contraction 64)
        f32x4 e[4][2];
        #pragma unroll
        for (int i = 0; i < 4; ++i)
            #pragma unroll
            for (int j = 0; j < 2; ++j) {
                e[i][j][0] = 0.f; e[i][j][1] = 0.f;
                e[i][j][2] = 0.f; e[i][j][3] = 0.f;
            }
        #pragma unroll
        for (int kk = 0; kk < 64; kk += 32) {
            int cb = (kk >> 3) + quad;
            bf16x8 av[4], bv[2];
            #pragma unroll
            for (int i = 0; i < 4; ++i) {
                int r = wm * 64 + i * 16 + r16;
                av[i] = *reinterpret_cast<const bf16x8*>(&Qs[r * 64 + ((cb ^ (r & 7)) * 8)]);
            }
            #pragma unroll
            for (int j = 0; j < 2; ++j) {
                int r = wn * 32 + j * 16 + r16;
                bv[j] = *reinterpret_cast<const bf16x8*>(&Ks[r * 64 + ((cb ^ (r & 7)) * 8)]);
            }
            #pragma unroll
            for (int i = 0; i < 4; ++i)
                #pragma unroll
                for (int j = 0; j < 2; ++j)
                    e[i][j] = __builtin_amdgcn_mfma_f32_16x16x32_bf16(av[i], bv[j], e[i][j], 0, 0, 0);
        }
        // exp + write to Es (C-frag: row=quad*4+r, col=r16; XOR-swizzled rows)
        #pragma unroll
        for (int i = 0; i < 4; ++i)
            #pragma unroll
            for (int j = 0; j < 2; ++j) {
                int lcol = wn * 32 + j * 16 + r16;
                #pragma unroll
                for (int r = 0; r < 4; ++r) {
                    int lrow = wm * 64 + i * 16 + quad * 4 + r;
                    float v = __expf(e[i][j][r] * 0.125f);
                    Es[lrow * 64 + (((lcol >> 3) ^ (lrow & 7)) * 8) + (lcol & 7)] = f2bf(v);
                }
            }
        __syncthreads();                       // Es ready

        // acc += E-chunk x Vs^T (contraction over s-chunk)
        #pragma unroll
        for (int kk = 0; kk < 64; kk += 32) {
            int cb = (kk >> 3) + quad;
            bf16x8 av[4], bv[2];
            #pragma unroll
            for (int i = 0; i < 4; ++i) {
                int r = wm * 64 + i * 16 + r16;
                av[i] = *reinterpret_cast<const bf16x8*>(&Es[r * 64 + ((cb ^ (r & 7)) * 8)]);
            }
            #pragma unroll
            for (int j = 0; j < 2; ++j) {
                int r = wn * 32 + j * 16 + r16;
                bv[j] = *reinterpret_cast<const bf16x8*>(&Vs[r * 64 + ((cb ^ (r & 7)) * 8)]);
            }
            #pragma unroll
            for (int i = 0; i < 4; ++i)
                #pragma unroll
                for (int j = 0; j < 2; ++j)
                    acc[i][j] = __builtin_amdgcn_mfma_f32_16x16x32_bf16(av[i], bv[j], acc[i][j], 0, 0, 0);
        }
        __syncthreads();                       // PV done; next stage may overwrite K/V
    }

    #pragma unroll
    for (int i = 0; i < 4; ++i)
        #pragma unroll
        for (int j = 0; j < 2; ++j) {
            int lcol = wn * 32 + j * 16 + r16;
            #pragma unroll
            for (int r = 0; r < 4; ++r) {
                int lrow = wm * 64 + i * 16 + quad * 4 + r;
                outp[(long)lrow * 1024 + lcol] = f2bf(acc[i][j][r]);
            }
        }
}

// ---------------- Vt *= 1/l over all 4 batches: csum [4][16][1024] ----------------
__global__ __launch_bounds__(256) void vscale_k(u16* __restrict__ Vt, const float* __restrict__ csum) {
    long idx = (long)blockIdx.x * 256 + threadIdx.x;   // grid 2048
    int slab = (int)(idx >> 17);
    int rem = (int)(idx & 131071);
    int hv = rem >> 7;
    int s8 = (rem & 127) * 8;
    const float* cs = csum + slab * 16384 + (hv >> 6) * 1024 + s8;
    u16* pv = Vt + (long)slab * 1048576 + (long)hv * 1024 + s8;
    ushort4 a = *reinterpret_cast<ushort4*>(pv);
    ushort4 b = *reinterpret_cast<ushort4*>(pv + 4);
    a.x = f2bf(bf2f(a.x) / cs[0]); a.y = f2bf(bf2f(a.y) / cs[1]);
    a.z = f2bf(bf2f(a.z) / cs[2]); a.w = f2bf(bf2f(a.w) / cs[3]);
    b.x = f2bf(bf2f(b.x) / cs[4]); b.y = f2bf(bf2f(b.y) / cs[5]);
    b.z = f2bf(bf2f(b.z) / cs[6]); b.w = f2bf(bf2f(b.w) / cs[7]);
    *reinterpret_cast<ushort4*>(pv) = a;
    *reinterpret_cast<ushort4*>(pv + 4) = b;
}

// ---------------- out = (sum of NP partial slabs + resid [+bias]) - mean - std ----------------
template<int NP, int BIAS>
__global__ __launch_bounds__(256) void addsn_k(const float* __restrict__ parts, long pstride,
                                               const float* __restrict__ resid,
                                               const float* __restrict__ bias,
                                               float* __restrict__ out) {
    __shared__ float sm[8];
    long row = blockIdx.x;
    int tid = threadIdx.x;
    float4 x = reinterpret_cast<const float4*>(resid + row * 1024)[tid];
    #pragma unroll
    for (int p = 0; p < NP; ++p) {
        float4 a = reinterpret_cast<const float4*>(parts + p * pstride + row * 1024)[tid];
        x.x += a.x; x.y += a.y; x.z += a.z; x.w += a.w;
    }
    if (BIAS) {
        float4 bb = reinterpret_cast<const float4*>(bias)[tid];
        x.x += bb.x; x.y += bb.y; x.z += bb.z; x.w += bb.w;
    }
    float s = x.x + x.y + x.z + x.w;
    for (int o = 32; o > 0; o >>= 1) s += __shfl_down(s, o, 64);
    int lane = tid & 63, w = tid >> 6;
    if (lane == 0) sm[w] = s;
    __syncthreads();
    float mean = (sm[0] + sm[1] + sm[2] + sm[3]) * (1.f / 1024.f);
    float d0 = x.x - mean, d1 = x.y - mean, d2 = x.z - mean, d3 = x.w - mean;
    float q = d0 * d0 + d1 * d1 + d2 * d2 + d3 * d3;
    for (int o = 32; o > 0; o >>= 1) q += __shfl_down(q, o, 64);
    if (lane == 0) sm[w + 4] = q;
    __syncthreads();
    float sd = sqrtf((sm[4] + sm[5] + sm[6] + sm[7]) * (1.f / 1023.f));
    float4 ov;
    ov.x = d0 - sd; ov.y = d1 - sd; ov.z = d2 - sd; ov.w = d3 - sd;
    reinterpret_cast<float4*>(out + row * 1024)[tid] = ov;
}

// ---------------- launcher ----------------

extern "C" void kernel_launch(void* const* d_in, const int* in_sizes, int n_in,
                              void* d_out, int out_size, void* d_ws, size_t ws_size,
                              hipStream_t stream) {
    (void)in_sizes; (void)n_in; (void)out_size; (void)ws_size;
    const float* xf   = (const float*)d_in[0];
    const float* yf   = (const float*)d_in[1];
    const float* Wq1  = (const float*)d_in[2];
    const float* Wk1  = (const float*)d_in[3];
    const float* Wv1  = (const float*)d_in[4];
    const float* Wo1  = (const float*)d_in[5];
    const float* Wq2  = (const float*)d_in[6];
    const float* Wk2  = (const float*)d_in[7];
    const float* Wv2  = (const float*)d_in[8];
    const float* Wo2  = (const float*)d_in[9];
    const float* W_in = (const float*)d_in[10];
    const float* b_in = (const float*)d_in[11];
    const float* W_out= (const float*)d_in[12];
    const float* b_out= (const float*)d_in[13];

    // workspace layout (~192 MB)
    char* p = (char*)d_ws;
    auto alloc = [&](size_t bytes) { char* r = p; p += bytes; return r; };
    u16*   yb    = (u16*)alloc(8388608);    // y bf16 (4096x1024)
    u16*   xb    = (u16*)alloc(8388608);    // x bf16
    u16*   W1cat = (u16*)alloc(8388608);    // [Wq1|Wk1|Wv1|Wq2]^T-packed (4096 x 1024)
    u16*   Wkv2t = (u16*)alloc(4194304);    // [Wk2|Wv2] (2048 x 1024)
    u16*   Wo1t  = (u16*)alloc(2097152);
    u16*   Wo2t  = (u16*)alloc(2097152);
    u16*   Winb  = (u16*)alloc(8388608);    // W_in (4096 x 1024) = Bt layout
    u16*   Woutb = (u16*)alloc(8388608);    // W_out (1024 x 4096) = Bt layout
    u16*   QKV   = (u16*)alloc(33554432);   // (4096 x 4096): [Q1|K1|V1|Q2] per (b,t)
    u16*   KV2   = (u16*)alloc(16777216);   // (4096 x 2048): [K2|V2]
    u16*   Vt    = (u16*)alloc(8388608);    // per b: (1024 hv x 1024 s), scaled by 1/l in place
    u16*   Pb    = (u16*)alloc(33554432);   // FFN hidden (4096x4096 bf16)
    float* csum  = (float*)alloc(262144);   // column sums l [4][16][1024]
    u16*   part  = (u16*)alloc(8388608);    // attn partial (4096 x 1024) bf16
    float* gout  = (float*)alloc(33554432); // fp32 split-K partials, 2 slabs of 16 MB
    float* out1  = (float*)alloc(16777216);

    // ---- converts + weight packs ----
    convert_f2b_k<<<4096, 256, 0, stream>>>(yf, yb);
    convert_f2b_k<<<4096, 256, 0, stream>>>(xf, xb);
    pack_perm_t<<<dim3(1, 16, 16), 256, 0, stream>>>(Wq1, W1cat,           1024, 64);
    pack_perm_t<<<dim3(1, 16, 16), 256, 0, stream>>>(Wk1, W1cat + 1048576, 1024, 64);
    pack_perm_t<<<dim3(1, 16, 16), 256, 0, stream>>>(Wv1, W1cat + 2097152, 1024, 64);
    pack_perm_t<<<dim3(1, 16, 16), 256, 0, stream>>>(Wq2, W1cat + 3145728, 1024, 64);
    pack_perm_t<<<dim3(1, 16, 16), 256, 0, stream>>>(Wk2, Wkv2t,           1024, 64);
    pack_perm_t<<<dim3(1, 16, 16), 256, 0, stream>>>(Wv2, Wkv2t + 1048576, 1024, 64);
    pack_perm_t<<<dim3(16, 16, 1), 256, 0, stream>>>(Wo1, Wo1t,            1024, 1024);
    pack_perm_t<<<dim3(16, 16, 1), 256, 0, stream>>>(Wo2, Wo2t,            1024, 1024);
    convert_f2b_k<<<4096, 256, 0, stream>>>(W_in,  Winb);
    convert_f2b_k<<<4096, 256, 0, stream>>>(W_out, Woutb);

    // attention core: all 4 batches per dispatch.
    auto run_attention = [&](const u16* Q, long ldq, long qbz,
                             const u16* Kp, long ldk, long kbz,
                             const u16* Vp, long ldv, long vbz) {
        transpose_k<<<dim3(16, 16, 4), 256, 0, stream>>>(Vp, ldv, vbz, Vt, 1024L, 1048576L);
        hipMemsetAsync(csum, 0, 262144, stream);
        // l-pass: exp column-sums, no stores. z=(b,h): zi=h (stride 64), zo=b.
        gemm_k<128,128,64,2,2,1,4,0,1><<<dim3(8, 8, 64), 256, 0, stream>>>(
            Q, ldq, 64L, qbz, Kp, ldk, 64L, kbz,
            (void*)Pb, 1024L, 0L, 0L, 16, 64, 0.125f, nullptr, csum);
        vscale_k<<<2048, 256, 0, stream>>>(Vt, csum);
        attn_pv_k<<<512, 256, 0, stream>>>(Q, ldq, qbz, Kp, ldk, kbz, Vt, part);
    };

    // ---- fused projections: QKV1 + Q2 (both consume y), N=4096 ----
    gemm_k<128,128,64,2,2,1,0,4,1><<<dim3(32 * 32), 256, 0, stream>>>(
        yb, 1024L, 0L, 0L, W1cat, 1024L, 0L, 0L, (void*)QKV, 4096L, 0L, 0L, 1, 1024, 1.0f, nullptr, nullptr);
    // K2/V2 from x, N=2048
    gemm_k<128,128,64,2,2,1,0,4,1><<<dim3(16 * 32), 256, 0, stream>>>(
        xb, 1024L, 0L, 0L, Wkv2t, 1024L, 0L, 0L, (void*)KV2, 2048L, 0L, 0L, 1, 1024, 1.0f, nullptr, nullptr);

    // ---- MHA1 (self-attn on y): Q/K/V at cols 0/1024/2048 of QKV ----
    run_attention(QKV, 4096L, 4194304L, QKV + 1024, 4096L, 4194304L, QKV + 2048, 4096L, 4194304L);
    gemm_k<128,64,64,2,2,0,0,4,2><<<dim3(2 * 512), 256, 0, stream>>>(
        part, 1024L, 0L, 512L, Wo1t, 1024L, 0L, 512L,
        (void*)gout, 1024L, 0L, 4194304L, 1, 512, 1.0f, nullptr, nullptr);
    addsn_k<2,0><<<4096, 256, 0, stream>>>(gout, 4194304L, yf, nullptr, out1);

    // ---- MHA2 (q from y at QKV col 3072; k/v from x in KV2) ----
    run_attention(QKV + 3072, 4096L, 4194304L, KV2, 2048L, 2097152L, KV2 + 1024, 2048L, 2097152L);
    gemm_k<128,64,64,2,2,0,0,4,2><<<dim3(2 * 512), 256, 0, stream>>>(
        part, 1024L, 0L, 512L, Wo2t, 1024L, 0L, 512L,
        (void*)gout, 1024L, 0L, 4194304L, 1, 512, 1.0f, nullptr, nullptr);
    addsn_k<2,0><<<4096, 256, 0, stream>>>(gout, 4194304L, out1, nullptr, (float*)d_out);

    // ---- FFN on y (hidden in Pb: 4096x4096 bf16) ----
    gemm_k<128,128,64,2,2,1,1,4,1><<<dim3(32 * 32), 256, 0, stream>>>(
        yb, 1024L, 0L, 0L, Winb, 1024L, 0L, 0L, (void*)Pb, 4096L, 0L, 0L, 1, 1024, 1.0f, b_in, nullptr);
    gemm_k<128,64,64,2,2,0,0,4,2><<<dim3(2 * 512), 256, 0, stream>>>(
        Pb, 4096L, 0L, 2048L, Woutb, 4096L, 0L, 2048L,
        (void*)gout, 1024L, 0L, 4194304L, 1, 2048, 1.0f, nullptr, nullptr);
    addsn_k<2,1><<<4096, 256, 0, stream>>>(gout, 4194304L, (const float*)d_out, b_out, (float*)d_out);
}